// Round 6
// baseline (347.315 us; speedup 1.0000x reference)
//
#include <hip/hip_runtime.h>

// ---------------------------------------------------------------------------
// OracleAD2D: per-variable LSTM encoder -> temporal softmax pooling -> MHSA
//             -> per-variable LSTM decoder.  B=64, L=128, N=32, D=128, H=4.
//
// Round-6: single fused dispatch.  Rounds 4/5 proved the recurrent step loop
// is latency-bound (instruction trims neutral), and the top-5 table proved
// dec < enc=107us -> ~65us of the 293us wall was inter-dispatch overhead.
// Fuse enc -> attn -> outproj -> dec into ONE kernel with device-scope
// atomic grid barriers (256 blocks, 1 block/CU, provably co-resident).
//  * enc/dec: grid slice = 32 n x 8 batch-tiles of 8; XCD swizzle n=blk&31.
//    Whh resident as f16 B-fragments (64 VGPR); pool/out dot via extra MFMA
//    tile in wave 0; bias as MFMA C operand; 1 intra-block barrier/step.
//  * MFMA layouts (m89/m91/m120-verified on gfx950):
//      A: lane holds A[m = lane&15][k = (lane>>4)*8 + j]   (8 f16)
//      B: lane holds B[n = lane&15][k = (lane>>4)*8 + j]   (8 f16)
//      D: lane reg r holds D[row = (lane>>4)*4 + r][col = lane&15]
// ---------------------------------------------------------------------------

typedef _Float16 h8  __attribute__((ext_vector_type(8)));
typedef _Float16 h4v __attribute__((ext_vector_type(4)));
typedef float    f4  __attribute__((ext_vector_type(4)));
typedef float    f2v __attribute__((ext_vector_type(2)));

#define DI __device__ __forceinline__

constexpr int NV  = 32;          // variables
constexpr int LT  = 128;         // sequence length
constexpr int DH  = 128;         // hidden
constexpr int GG  = 4 * DH;      // 512 gate rows
constexpr int BR  = 8;           // batch rows per block (enc/dec)
constexpr int NW  = 8;           // waves per block
constexpr int TPB = NW * 64;     // 512 threads
constexpr int HSTR = DH + 8;     // padded f16 row stride (16B-aligned)
constexpr int NBLK = 256;        // grid size (1 block/CU -> co-resident)
constexpr float LOG2E = 1.4426950408889634f;

constexpr int CS2 = DH + 8;     // attn: f16 stride for staged C
constexpr int QS  = 40;         // attn: f16 stride for q/k/vT/P

// shared-memory overlay offsets (bytes)
constexpr int SM_HBUF = 0;                       // 2*16*HSTR f16   = 8704
constexpr int SM_XS   = 8704;                    // enc xs / dec obuf = 4064
constexpr int SM_PFIN = 8704 + 4064;             // enc pfin          = 64
constexpr int SM_QS   = 8704;                    // attn qs  32*QS f16 = 2560
constexpr int SM_KS   = 8704 + 2560;             // attn ks           = 2560
constexpr int SM_VT   = 8704 + 5120;             // attn vT           = 2560
constexpr int SM_S    = 8704 + 7680;             // attn S 32*33 f32  = 4224
constexpr int SM_P    = 8704 + 7680 + 4224;      // attn P            = 2560
constexpr int SM_SZ   = 23424;

DI float rcp_(float x) { return __builtin_amdgcn_rcpf(x); }
DI float ex2_(float x) { return __builtin_amdgcn_exp2f(x); }

DI float tanh_(float x) {
    float xc = fminf(fmaxf(x, -20.0f), 20.0f);
    float E = ex2_(2.0f * LOG2E * xc);                  // e^{2x}
    return (E - 1.0f) * rcp_(E + 1.0f);
}

// Pre-scaled LSTM cell (scales folded into weights):
//   iv = -log2e*i, fv = -log2e*f, gv = 2log2e*g, ov = -log2e*o
DI float lstm_cell(float iv, float fv, float gv, float ov, float& c) {
    float Ai = ex2_(iv);                 // e^{-i}
    float Af = ex2_(fv);                 // e^{-f}
    float Bg = ex2_(gv);                 // e^{2g}
    float ai1 = 1.0f + Ai, af1 = 1.0f + Af, bg1 = 1.0f + Bg;
    float P = ai1 * bg1;
    float N = fmaf(c, P, (Bg - 1.0f) * af1);
    c = N * rcp_(P * af1);
    float cc = fminf(fmaxf(c, -20.0f), 20.0f);
    float Ec = ex2_(2.0f * LOG2E * cc);  // e^{2c}
    float Eo = ex2_(ov);                 // e^{-o}
    return (Ec - 1.0f) * rcp_((1.0f + Eo) * (1.0f + Ec)); // sig(o)*tanh(c)
}

DI h8 cvt8(f4 a, f4 b) {
    h8 r;
    r[0] = (_Float16)a[0]; r[1] = (_Float16)a[1];
    r[2] = (_Float16)a[2]; r[3] = (_Float16)a[3];
    r[4] = (_Float16)b[0]; r[5] = (_Float16)b[1];
    r[6] = (_Float16)b[2]; r[7] = (_Float16)b[3];
    return r;
}
DI h8 cvt8s(f4 a, f4 b, float s) {
    h8 r;
    r[0] = (_Float16)(a[0] * s); r[1] = (_Float16)(a[1] * s);
    r[2] = (_Float16)(a[2] * s); r[3] = (_Float16)(a[3] * s);
    r[4] = (_Float16)(b[0] * s); r[5] = (_Float16)(b[1] * s);
    r[6] = (_Float16)(b[2] * s); r[7] = (_Float16)(b[3] * s);
    return r;
}

// gate exp2 scales (torch order i,f,g,o)
__constant__ float GSC[4] = {-LOG2E, -LOG2E, 2.0f * LOG2E, -LOG2E};

// Device-scope grid barrier.  Safe: 256 blocks x 512 thr x 23.4 KB LDS x
// <=256 VGPR -> exactly 1 block/CU on 256 CUs, all co-resident.
// __threadfence (agent-scope) gives cross-XCD L2 writeback/invalidate.
DI void gsync(unsigned* bar, int k) {
    __syncthreads();                 // compiler drains vmcnt before s_barrier
    if (threadIdx.x == 0) {
        __threadfence();             // release: prior writes visible device-wide
        atomicAdd(bar + k, 1u);
        while (atomicAdd(bar + k, 0u) < (unsigned)NBLK)
            __builtin_amdgcn_s_sleep(2);
        __threadfence();             // acquire: invalidate stale L1/L2 lines
    }
    __syncthreads();
}

// ---------------------------------------------------------------------------
__global__ __launch_bounds__(TPB, 2)
void fused_kernel(const float* __restrict__ X,      // (B,L,N)
                  const float* __restrict__ Wih,    // (N,512)
                  const float* __restrict__ Whh,    // (N,512,128)
                  const float* __restrict__ bih,    // (N,512)
                  const float* __restrict__ bhh,    // (N,512)
                  const float* __restrict__ poolw,  // (N,128)
                  const float* __restrict__ Wqkv,   // (384,128)
                  const float* __restrict__ bqkv,   // (384)
                  const float* __restrict__ Wo,     // (128,128)
                  const float* __restrict__ bo,     // (128)
                  const float* __restrict__ ihW,    // (N,D,D)
                  const float* __restrict__ ihb,    // (N,D)
                  const float* __restrict__ icW,    // (N,D,D)
                  const float* __restrict__ icb,    // (N,D)
                  const float* __restrict__ dWhh,   // (N,512,128)
                  const float* __restrict__ dbih,   // (N,512)
                  const float* __restrict__ dbhh,   // (N,512)
                  const float* __restrict__ outW,   // (N,128)
                  const float* __restrict__ outb,   // (N)
                  float* __restrict__ Cpool,        // (B,N,D) staging (=out)
                  float* __restrict__ Cstar,        // (B,N,D) staging
                  float* __restrict__ recon,        // (B,127,N)
                  float* __restrict__ pred,         // (B,N)
                  unsigned* __restrict__ bar)       // 3 zeroed counters
{
    __shared__ __align__(16) char smem[SM_SZ];

    const int blk  = blockIdx.x;
    const int tid  = threadIdx.x;
    const int wv   = tid >> 6;
    const int lane = tid & 63;
    const int quad = lane >> 4;
    const int l16  = lane & 15;
    const int dmy  = wv * 16 + l16;

    // =======================================================================
    // Phase 1: encoder (127 LSTM steps + online softmax pooling) -> Cpool
    // =======================================================================
    {
        const int n  = blk & 31;            // XCD swizzle: same n -> same XCD
        const int b0 = (blk >> 5) * BR;

        _Float16 (*hbuf)[16 * HSTR] = (_Float16(*)[16 * HSTR])(smem + SM_HBUF);
        float* xs = (float*)(smem + SM_XS);
        float (*pfin)[BR] = (float(*)[BR])(smem + SM_PFIN);

        h8 Wf[4][4];
        float wihr[4];
        f4 bsp[4];
#pragma unroll
        for (int g4 = 0; g4 < 4; ++g4) {
            const float s = GSC[g4];
            const int g = g4 * DH + dmy;
            const float* wrow = Whh + (size_t)(n * GG + g) * DH;
#pragma unroll
            for (int kc = 0; kc < 4; ++kc) {
                f4 w0 = *(const f4*)(wrow + kc * 32 + quad * 8);
                f4 w1 = *(const f4*)(wrow + kc * 32 + quad * 8 + 4);
                Wf[g4][kc] = cvt8s(w0, w1, s);
            }
            wihr[g4] = Wih[n * GG + g] * s;
            const float bb = (bih[n * GG + g] + bhh[n * GG + g]) * s;
            bsp[g4] = (f4){bb, bb, bb, bb};
        }
        h8 Bp[4];
#pragma unroll
        for (int kc = 0; kc < 4; ++kc) {
            if (l16 == 0) {
                f4 p0 = *(const f4*)(poolw + n * DH + kc * 32 + quad * 8);
                f4 p1 = *(const f4*)(poolw + n * DH + kc * 32 + quad * 8 + 4);
                Bp[kc] = cvt8s(p0, p1, LOG2E);
            } else {
                Bp[kc] = (h8)(_Float16)0.0f;
            }
        }

        for (int i = tid; i < (LT - 1) * BR; i += TPB)
            xs[i] = X[((size_t)(b0 + (i & 7)) * LT + (i >> 3)) * NV + n];
        for (int i = tid; i < 2 * 16 * HSTR; i += TPB)
            ((_Float16*)hbuf)[i] = (_Float16)0.0f;
        __syncthreads();

        float cst[2]   = {0.f, 0.f};
        float lsum[2]  = {0.f, 0.f};
        float acc[2]   = {0.f, 0.f};
        float hprev[2] = {0.f, 0.f};

        for (int t = 0; t < LT - 1; ++t) {
            const _Float16* hb = hbuf[t & 1];
            h8 a[4];
#pragma unroll
            for (int kc = 0; kc < 4; ++kc)
                a[kc] = *(const h8*)(hb + l16 * HSTR + kc * 32 + quad * 8);

            f4 pre[4];
#pragma unroll
            for (int g4 = 0; g4 < 4; ++g4)
                pre[g4] = __builtin_amdgcn_mfma_f32_16x16x32_f16(
                    a[0], Wf[g4][0], bsp[g4], 0, 0, 0);
#pragma unroll
            for (int kc = 1; kc < 4; ++kc)
#pragma unroll
                for (int g4 = 0; g4 < 4; ++g4)
                    pre[g4] = __builtin_amdgcn_mfma_f32_16x16x32_f16(
                        a[kc], Wf[g4][kc], pre[g4], 0, 0, 0);

            if (wv == 0) {
                f4 sp = {0.f, 0.f, 0.f, 0.f};
#pragma unroll
                for (int kc = 0; kc < 4; ++kc)
                    sp = __builtin_amdgcn_mfma_f32_16x16x32_f16(a[kc], Bp[kc], sp, 0, 0, 0);
                if (l16 == 0) {
                    pfin[t & 1][quad * 2 + 0] = ex2_(sp[0]);
                    pfin[t & 1][quad * 2 + 1] = ex2_(sp[1]);
                }
            }

            const f2v xv = *(const f2v*)(xs + t * BR + quad * 2);
            float hv[2];
#pragma unroll
            for (int r = 0; r < 2; ++r) {
                hv[r] = lstm_cell(fmaf(xv[r], wihr[0], pre[0][r]),
                                  fmaf(xv[r], wihr[1], pre[1][r]),
                                  fmaf(xv[r], wihr[2], pre[2][r]),
                                  fmaf(xv[r], wihr[3], pre[3][r]), cst[r]);
            }

            _Float16* hn = hbuf[(t + 1) & 1];
#pragma unroll
            for (int r = 0; r < 2; ++r)
                hn[(quad * 4 + r) * HSTR + dmy] = (_Float16)hv[r];
            __syncthreads();

            if (t > 0) {
#pragma unroll
                for (int r = 0; r < 2; ++r) {
                    const float p = pfin[t & 1][quad * 2 + r];
                    lsum[r] += p;
                    acc[r] = fmaf(p, hprev[r], acc[r]);
                }
            }
#pragma unroll
            for (int r = 0; r < 2; ++r) hprev[r] = hv[r];
        }

        if (wv == 0) {
            const _Float16* hb = hbuf[(LT - 1) & 1];
            h8 a[4];
#pragma unroll
            for (int kc = 0; kc < 4; ++kc)
                a[kc] = *(const h8*)(hb + l16 * HSTR + kc * 32 + quad * 8);
            f4 sp = {0.f, 0.f, 0.f, 0.f};
#pragma unroll
            for (int kc = 0; kc < 4; ++kc)
                sp = __builtin_amdgcn_mfma_f32_16x16x32_f16(a[kc], Bp[kc], sp, 0, 0, 0);
            if (l16 == 0) {
                pfin[(LT - 1) & 1][quad * 2 + 0] = ex2_(sp[0]);
                pfin[(LT - 1) & 1][quad * 2 + 1] = ex2_(sp[1]);
            }
        }
        __syncthreads();
#pragma unroll
        for (int r = 0; r < 2; ++r) {
            const float p = pfin[(LT - 1) & 1][quad * 2 + r];
            lsum[r] += p;
            acc[r] = fmaf(p, hprev[r], acc[r]);
        }
#pragma unroll
        for (int r = 0; r < 2; ++r) {
            const int b = b0 + quad * 2 + r;
            Cpool[((size_t)b * NV + n) * DH + dmy] = acc[r] * rcp_(lsum[r]);
        }
    }

    gsync(bar, 0);

    // =======================================================================
    // Phase 2: attention (b, head) -> Astage (= Cstar region)
    // =======================================================================
    {
        const int b  = blk >> 2;
        const int hh = blk & 3;

        _Float16 (*Cb)[CS2] = (_Float16(*)[CS2])(smem + SM_HBUF);
        _Float16 (*qs)[QS]  = (_Float16(*)[QS])(smem + SM_QS);
        _Float16 (*ks)[QS]  = (_Float16(*)[QS])(smem + SM_KS);
        _Float16 (*vT)[QS]  = (_Float16(*)[QS])(smem + SM_VT);
        float    (*S)[NV+1] = (float(*)[NV+1])(smem + SM_S);
        _Float16 (*P)[QS]   = (_Float16(*)[QS])(smem + SM_P);

        for (int i = tid; i < NV * DH / 4; i += TPB) {
            const int nn = i >> 5, d4 = (i & 31) * 4;
            f4 v = *(const f4*)(Cpool + ((size_t)b * NV + nn) * DH + d4);
            h4v hv4;
            hv4[0] = (_Float16)v[0]; hv4[1] = (_Float16)v[1];
            hv4[2] = (_Float16)v[2]; hv4[3] = (_Float16)v[3];
            *(h4v*)(&Cb[nn][d4]) = hv4;
        }
        __syncthreads();

        const int m0 = ((wv & 3) >> 1) * 16;
        const int n0 = (wv & 1) * 16;

        if (tid < 256) {
            h8 a[4];
#pragma unroll
            for (int kc = 0; kc < 4; ++kc)
                a[kc] = *(const h8*)(&Cb[m0 + l16][kc * 32 + quad * 8]);
#pragma unroll
            for (int mat = 0; mat < 3; ++mat) {      // 0=q, 1=k, 2=v
                const int rbase = mat * DH + hh * 32;
                const float* wrow = Wqkv + (size_t)(rbase + n0 + l16) * DH;
                const float bias  = bqkv[rbase + n0 + l16];
                f4 acc = {bias, bias, bias, bias};
#pragma unroll
                for (int kc = 0; kc < 4; ++kc) {
                    f4 w0 = *(const f4*)(wrow + kc * 32 + quad * 8);
                    f4 w1 = *(const f4*)(wrow + kc * 32 + quad * 8 + 4);
                    acc = __builtin_amdgcn_mfma_f32_16x16x32_f16(a[kc], cvt8(w0, w1), acc, 0, 0, 0);
                }
#pragma unroll
                for (int r = 0; r < 4; ++r) {
                    const int tok = m0 + quad * 4 + r, col = n0 + l16;
                    if (mat == 0)      qs[tok][col] = (_Float16)acc[r];
                    else if (mat == 1) ks[tok][col] = (_Float16)acc[r];
                    else               vT[col][tok] = (_Float16)acc[r];
                }
            }
        }
        __syncthreads();

        if (tid < 256) {
            h8 aq = *(const h8*)(&qs[m0 + l16][quad * 8]);
            h8 bk = *(const h8*)(&ks[n0 + l16][quad * 8]);
            f4 sc = {0.f, 0.f, 0.f, 0.f};
            sc = __builtin_amdgcn_mfma_f32_16x16x32_f16(aq, bk, sc, 0, 0, 0);
#pragma unroll
            for (int r = 0; r < 4; ++r)
                S[m0 + quad * 4 + r][n0 + l16] = sc[r] * 0.17677669529663687f;
        }
        __syncthreads();

        if (tid < NV) {
            float mx = -1e30f;
            for (int j = 0; j < NV; ++j) mx = fmaxf(mx, S[tid][j]);
            float l = 0.0f;
            float p[NV];
#pragma unroll
            for (int j = 0; j < NV; ++j) {
                p[j] = ex2_(LOG2E * (S[tid][j] - mx));
                l += p[j];
            }
            const float rl = rcp_(l);
#pragma unroll
            for (int j = 0; j < NV; ++j) P[tid][j] = (_Float16)(p[j] * rl);
        }
        __syncthreads();

        if (tid < 256) {
            h8 ap = *(const h8*)(&P[m0 + l16][quad * 8]);
            h8 bv = *(const h8*)(&vT[n0 + l16][quad * 8]);
            f4 av = {0.f, 0.f, 0.f, 0.f};
            av = __builtin_amdgcn_mfma_f32_16x16x32_f16(ap, bv, av, 0, 0, 0);
#pragma unroll
            for (int r = 0; r < 4; ++r) {
                const int tok = m0 + quad * 4 + r;
                Cstar[((size_t)b * NV + tok) * DH + hh * 32 + n0 + l16] = av[r];
            }
        }
    }

    gsync(bar, 1);

    // =======================================================================
    // Phase 3: out-projection, in place on Cstar (128 row-tiles of 16)
    // =======================================================================
    if (blk < 128) {                      // uniform branch: safe w/ barriers
        const int mb = blk * 16;
        _Float16 (*As)[HSTR] = (_Float16(*)[HSTR])(smem + SM_HBUF);

        {
            const int rr = tid >> 5, d4 = (tid & 31) * 4;   // 512 = 16 x 32
            f4 v = *(const f4*)(Cstar + ((size_t)(mb + rr)) * DH + d4);
            h4v hv4;
            hv4[0] = (_Float16)v[0]; hv4[1] = (_Float16)v[1];
            hv4[2] = (_Float16)v[2]; hv4[3] = (_Float16)v[3];
            *(h4v*)(&As[rr][d4]) = hv4;
        }
        __syncthreads();

        h8 a[4];
#pragma unroll
        for (int kc = 0; kc < 4; ++kc)
            a[kc] = *(const h8*)(&As[l16][kc * 32 + quad * 8]);

        const int n0 = wv * 16;           // 8 waves x 16 = 128 cols
        const float* wrow = Wo + (size_t)(n0 + l16) * DH;
        const float bias  = bo[n0 + l16];
        f4 acc = {bias, bias, bias, bias};
#pragma unroll
        for (int kc = 0; kc < 4; ++kc) {
            f4 w0 = *(const f4*)(wrow + kc * 32 + quad * 8);
            f4 w1 = *(const f4*)(wrow + kc * 32 + quad * 8 + 4);
            acc = __builtin_amdgcn_mfma_f32_16x16x32_f16(a[kc], cvt8(w0, w1), acc, 0, 0, 0);
        }
#pragma unroll
        for (int r = 0; r < 4; ++r)
            Cstar[((size_t)(mb + quad * 4 + r)) * DH + n0 + l16] = acc[r];
    }

    gsync(bar, 2);

    // =======================================================================
    // Phase 4: decoder (init + 128 zero-input LSTM steps) -> recon / pred
    // =======================================================================
    {
        const int n  = blk & 31;
        const int b0 = (blk >> 5) * BR;

        _Float16 (*hbuf)[16 * HSTR] = (_Float16(*)[16 * HSTR])(smem + SM_HBUF);
        float (*obuf)[BR] = (float(*)[BR])(smem + SM_XS);

        h8 Wf[4][4];
        f4 bsp[4];
#pragma unroll
        for (int g4 = 0; g4 < 4; ++g4) {
            const float s = GSC[g4];
            const int g = g4 * DH + dmy;
            const float* wrow = dWhh + (size_t)(n * GG + g) * DH;
#pragma unroll
            for (int kc = 0; kc < 4; ++kc) {
                f4 w0 = *(const f4*)(wrow + kc * 32 + quad * 8);
                f4 w1 = *(const f4*)(wrow + kc * 32 + quad * 8 + 4);
                Wf[g4][kc] = cvt8s(w0, w1, s);
            }
            const float bb = (dbih[n * GG + g] + dbhh[n * GG + g]) * s;
            bsp[g4] = (f4){bb, bb, bb, bb};
        }
        h8 Bo[4];
#pragma unroll
        for (int kc = 0; kc < 4; ++kc) {
            if (l16 == 0) {
                f4 p0 = *(const f4*)(outW + n * DH + kc * 32 + quad * 8);
                f4 p1 = *(const f4*)(outW + n * DH + kc * 32 + quad * 8 + 4);
                Bo[kc] = cvt8(p0, p1);
            } else {
                Bo[kc] = (h8)(_Float16)0.0f;
            }
        }
        const float ob = outb[n];

        for (int i = tid; i < 2 * 16 * HSTR; i += TPB)
            ((_Float16*)hbuf)[i] = (_Float16)0.0f;
        __syncthreads();
        if (tid < 256) {
            const int j = tid >> 5, d4 = (tid & 31) * 4;    // 8 rows x 32 f4
            const int row = (j >> 1) * 4 + (j & 1);
            f4 v = *(const f4*)(Cstar + ((size_t)(b0 + j) * NV + n) * DH + d4);
            h4v hv4;
            hv4[0] = (_Float16)v[0]; hv4[1] = (_Float16)v[1];
            hv4[2] = (_Float16)v[2]; hv4[3] = (_Float16)v[3];
            *(h4v*)(&hbuf[0][row * HSTR + d4]) = hv4;
        }
        __syncthreads();

        float cst[2], hv0[2];
        {
            h8 a[4];
#pragma unroll
            for (int kc = 0; kc < 4; ++kc)
                a[kc] = *(const h8*)(hbuf[0] + l16 * HSTR + kc * 32 + quad * 8);
            const float bh = ihb[n * DH + dmy];
            const float bc = icb[n * DH + dmy];
            f4 Ph = {bh, bh, bh, bh};
            f4 Pc = {bc, bc, bc, bc};
            const float* hrow = ihW + (size_t)(n * DH + dmy) * DH;
            const float* crow = icW + (size_t)(n * DH + dmy) * DH;
#pragma unroll
            for (int kc = 0; kc < 4; ++kc) {
                f4 w0 = *(const f4*)(hrow + kc * 32 + quad * 8);
                f4 w1 = *(const f4*)(hrow + kc * 32 + quad * 8 + 4);
                Ph = __builtin_amdgcn_mfma_f32_16x16x32_f16(a[kc], cvt8(w0, w1), Ph, 0, 0, 0);
                f4 u0 = *(const f4*)(crow + kc * 32 + quad * 8);
                f4 u1 = *(const f4*)(crow + kc * 32 + quad * 8 + 4);
                Pc = __builtin_amdgcn_mfma_f32_16x16x32_f16(a[kc], cvt8(u0, u1), Pc, 0, 0, 0);
            }
#pragma unroll
            for (int r = 0; r < 2; ++r) {
                hv0[r] = tanh_(Ph[r]);
                cst[r] = tanh_(Pc[r]);
            }
        }
        __syncthreads();
#pragma unroll
        for (int r = 0; r < 2; ++r)
            hbuf[0][(quad * 4 + r) * HSTR + dmy] = (_Float16)hv0[r];
        __syncthreads();

        for (int t = 0; t < LT; ++t) {
            const _Float16* hb = hbuf[t & 1];
            h8 a[4];
#pragma unroll
            for (int kc = 0; kc < 4; ++kc)
                a[kc] = *(const h8*)(hb + l16 * HSTR + kc * 32 + quad * 8);

            f4 pre[4];
#pragma unroll
            for (int g4 = 0; g4 < 4; ++g4)
                pre[g4] = __builtin_amdgcn_mfma_f32_16x16x32_f16(
                    a[0], Wf[g4][0], bsp[g4], 0, 0, 0);
#pragma unroll
            for (int kc = 1; kc < 4; ++kc)
#pragma unroll
                for (int g4 = 0; g4 < 4; ++g4)
                    pre[g4] = __builtin_amdgcn_mfma_f32_16x16x32_f16(
                        a[kc], Wf[g4][kc], pre[g4], 0, 0, 0);

            if (wv == 0 && t > 0) {
                f4 so = {0.f, 0.f, 0.f, 0.f};
#pragma unroll
                for (int kc = 0; kc < 4; ++kc)
                    so = __builtin_amdgcn_mfma_f32_16x16x32_f16(a[kc], Bo[kc], so, 0, 0, 0);
                if (l16 == 0) {
                    obuf[t - 1][quad * 2 + 0] = so[0] + ob;
                    obuf[t - 1][quad * 2 + 1] = so[1] + ob;
                }
            }

            float hv[2];
#pragma unroll
            for (int r = 0; r < 2; ++r)
                hv[r] = lstm_cell(pre[0][r], pre[1][r], pre[2][r], pre[3][r], cst[r]);

            _Float16* hn = hbuf[(t + 1) & 1];
#pragma unroll
            for (int r = 0; r < 2; ++r)
                hn[(quad * 4 + r) * HSTR + dmy] = (_Float16)hv[r];
            __syncthreads();
        }

        if (wv == 0) {
            const _Float16* hb = hbuf[LT & 1];
            h8 a[4];
#pragma unroll
            for (int kc = 0; kc < 4; ++kc)
                a[kc] = *(const h8*)(hb + l16 * HSTR + kc * 32 + quad * 8);
            f4 so = {0.f, 0.f, 0.f, 0.f};
#pragma unroll
            for (int kc = 0; kc < 4; ++kc)
                so = __builtin_amdgcn_mfma_f32_16x16x32_f16(a[kc], Bo[kc], so, 0, 0, 0);
            if (l16 == 0) {
                pred[(size_t)(b0 + quad * 2 + 0) * NV + n] = so[0] + ob;
                pred[(size_t)(b0 + quad * 2 + 1) * NV + n] = so[1] + ob;
            }
        }

        if (tid < LT - 1) {
#pragma unroll
            for (int b = 0; b < BR; ++b)
                recon[((size_t)(b0 + b) * (LT - 1) + tid) * NV + n] = obuf[tid][b];
        }
    }
}

// ---------------------------------------------------------------------------
extern "C" void kernel_launch(void* const* d_in, const int* in_sizes, int n_in,
                              void* d_out, int out_size, void* d_ws, size_t ws_size,
                              hipStream_t stream) {
    (void)in_sizes; (void)n_in; (void)ws_size; (void)out_size;

    const float* X     = (const float*)d_in[0];
    const float* eWih  = (const float*)d_in[1];
    const float* eWhh  = (const float*)d_in[2];
    const float* ebih  = (const float*)d_in[3];
    const float* ebhh  = (const float*)d_in[4];
    const float* poolw = (const float*)d_in[5];
    // d_in[6] = pool_b: cancels inside softmax over t -> unused
    const float* Wqkv  = (const float*)d_in[7];
    const float* bqkv  = (const float*)d_in[8];
    const float* Wo    = (const float*)d_in[9];
    const float* bo    = (const float*)d_in[10];
    const float* dihW  = (const float*)d_in[11];
    const float* dihb  = (const float*)d_in[12];
    const float* dicW  = (const float*)d_in[13];
    const float* dicb  = (const float*)d_in[14];
    // d_in[15] = dec_Wih: decoder input is identically zero -> unused
    const float* dWhh  = (const float*)d_in[16];
    const float* dbih  = (const float*)d_in[17];
    const float* dbhh  = (const float*)d_in[18];
    const float* doutW = (const float*)d_in[19];
    const float* doutb = (const float*)d_in[20];

    float* out   = (float*)d_out;
    float* recon = out;                              // 64*127*32 = 260096
    float* pred  = out + 64 * 127 * 32;              // 2048
    float* Cstar = out + 64 * 127 * 32 + 64 * 32;    // 262144 floats region
    float* Cpool = out;      // staged in recon+pred region, same size

    unsigned* bar = (unsigned*)d_ws;
    hipMemsetAsync(bar, 0, 4 * sizeof(unsigned), stream);   // zero barrier ctrs

    fused_kernel<<<dim3(NBLK), dim3(TPB), 0, stream>>>(
        X, eWih, eWhh, ebih, ebhh, poolw,
        Wqkv, bqkv, Wo, bo,
        dihW, dihb, dicW, dicb,
        dWhh, dbih, dbhh, doutW, doutb,
        Cpool, Cstar, recon, pred, bar);
}